// Round 5
// baseline (477.306 us; speedup 1.0000x reference)
//
#include <hip/hip_runtime.h>
#include <hip/hip_fp16.h>
#include <cstdint>
#include <cstddef>

typedef _Float16 f16x8 __attribute__((ext_vector_type(8)));
typedef _Float16 f16x4 __attribute__((ext_vector_type(4)));
typedef float    f32x4 __attribute__((ext_vector_type(4)));

// ---------------------------------------------------------------------------
// fake-quant with fractional bit-width interpolation (matches jax reference)
// ---------------------------------------------------------------------------
__device__ __forceinline__ float quant_interp(float v, float alpha) {
    float a    = fmaxf(alpha, 1.0f);
    float blo  = floorf(a);
    float frac = a - blo;
    float slo  = exp2f(blo) - 1.0f;
    float shi  = 2.0f * slo + 1.0f;
    float rslo = __builtin_amdgcn_rcpf(slo);
    float rshi = __builtin_amdgcn_rcpf(shi);
    float c    = fminf(fmaxf(v, -1.0f), 1.0f);
    float qlo  = rintf(c * slo) * rslo;
    float qhi  = rintf(c * shi) * rshi;
    return (1.0f - frac) * qlo + frac * qhi;
}

// ---------------------------------------------------------------------------
// column mean of alpha_a [OUT][IN] -> a_feat [IN], deterministic two-pass
// ---------------------------------------------------------------------------
__global__ void colsum_partial_kernel(const float* __restrict__ aA,
                                      float* __restrict__ partial,
                                      int IN, int rows_per) {
    int col = blockIdx.x * blockDim.x + threadIdx.x;
    size_t r0 = (size_t)blockIdx.y * rows_per;
    float s = 0.f;
    for (int r = 0; r < rows_per; ++r)
        s += aA[(r0 + r) * (size_t)IN + col];
    partial[(size_t)blockIdx.y * IN + col] = s;
}

__global__ void colsum_final_kernel(const float* __restrict__ partial,
                                    float* __restrict__ afeat,
                                    int IN, int nchunk, float inv) {
    int col = blockIdx.x * blockDim.x + threadIdx.x;
    float s = 0.f;
    for (int c = 0; c < nchunk; ++c)
        s += partial[(size_t)c * IN + col];
    afeat[col] = s * inv;
}

// ---------------------------------------------------------------------------
// quantize x [M][IN], per-column alpha -> fp16.
// Each thread owns 4 FIXED columns (params computed once: exp2/rcp/floor
// amortized over rows) and strides over M/512 rows. Coalesced: consecutive
// threads -> consecutive 16B column chunks.
// ---------------------------------------------------------------------------
__global__ void quant_x_kernel(const float* __restrict__ x,
                               const float* __restrict__ afeat,
                               f16x4* __restrict__ qx, int IN, int M) {
    const int nchunk = IN >> 2;
    const int T  = blockIdx.x * blockDim.x + threadIdx.x;
    const int cc = T % nchunk;
    const int rg = T / nchunk;
    const int nrg = ((int)gridDim.x * (int)blockDim.x) / nchunk;
    const int rows_per = M / nrg;

    f32x4 av = *(const f32x4*)(afeat + cc * 4);
    f32x4 frac, slo, shi, rslo, rshi;
    #pragma unroll
    for (int j = 0; j < 4; ++j) {
        float a   = fmaxf(av[j], 1.0f);
        float blo = floorf(a);
        frac[j] = a - blo;
        slo[j]  = exp2f(blo) - 1.0f;
        shi[j]  = 2.0f * slo[j] + 1.0f;
        rslo[j] = __builtin_amdgcn_rcpf(slo[j]);
        rshi[j] = __builtin_amdgcn_rcpf(shi[j]);
    }
    const int r0 = rg * rows_per;
    for (int r = r0; r < r0 + rows_per; ++r) {
        f32x4 xv = *(const f32x4*)(x + (size_t)r * IN + cc * 4);
        f16x4 o;
        #pragma unroll
        for (int j = 0; j < 4; ++j) {
            float c = fminf(fmaxf(xv[j], -1.0f), 1.0f);
            float q = (1.0f - frac[j]) * (rintf(c * slo[j]) * rslo[j])
                    + frac[j]        * (rintf(c * shi[j]) * rshi[j]);
            o[j] = (_Float16)q;
        }
        qx[(size_t)r * nchunk + cc] = o;
    }
}

__global__ void quant_w_kernel(const float* __restrict__ w,
                               const float* __restrict__ aw,
                               f16x4* __restrict__ qw, size_t n4) {
    size_t i = (size_t)blockIdx.x * blockDim.x + threadIdx.x;
    size_t stride = (size_t)gridDim.x * blockDim.x;
    for (; i < n4; i += stride) {
        f32x4 wv = *(const f32x4*)(w + i * 4);
        f32x4 av = *(const f32x4*)(aw + i * 4);
        f16x4 o;
        #pragma unroll
        for (int j = 0; j < 4; ++j) o[j] = (_Float16)quant_interp(wv[j], av[j]);
        qw[i] = o;
    }
}

// ---------------------------------------------------------------------------
// 256x256 NT GEMM, fp16 in / fp32 out — m201-style 4-phase/K-tile pipeline.
//   8 waves = 2(M) x 4(N); wave tile 128x64; acc[8][4] f32x4.
//   Phase p: {ds_read one operand subtile || stage one half-tile of t+2 ||
//   16 MFMA for quadrant p}, bracketed by [bar; lgkm0; schedbar] before MFMA
//   and [vmcnt(12); bar] after. Reads: P0:A0(8) P1:B1(4) P2:A1(8) P3:B0(t+1)(4)
//   = 24 b128/wave/tile (sharing minimum). Stages (dist-2): P0:B0(t+2)
//   P1:A0(t+2) P2:B1(t+2) P3:A1(t+2) — each overwrites a region whose reads
//   drained at the PREVIOUS phase's lgkmcnt(0)+barrier (1-barrier WAR).
//   FIFO ledger: 6 half-tiles (12 loads, ~96KB) in flight -> every phase-end
//   gate is exactly vmcnt(12), placed BEFORE the barrier (per-wave vmcnt +
//   barrier publishes all waves' staged slices). Last 2 tiles: stages get
//   skipped -> queue shrinks -> counted gates would under-wait -> vmcnt(0).
//   XOR slot swizzle: phys slot = logical ^ (row&7); inverse applied to the
//   GLOBAL source, linear LDS dest (rule #21). 0 bank conflicts (measured).
// ---------------------------------------------------------------------------
__device__ __forceinline__ void gload_lds16(const void* g, void* l) {
    __builtin_amdgcn_global_load_lds(
        (const __attribute__((address_space(1))) void*)g,
        (__attribute__((address_space(3))) void*)l, 16, 0, 0);
}

__device__ __forceinline__ f16x8 lds_frag(const _Float16* buf, int row, int ks, int hi) {
    const int sl = (ks * 4 + hi) ^ (row & 7);
    return *(const f16x8*)((const char*)buf + row * 128 + sl * 16);
}

#define GATE(N)  asm volatile("s_waitcnt vmcnt(" N ")" ::: "memory")
#define LGKM0()  asm volatile("s_waitcnt lgkmcnt(0)" ::: "memory")
#define SCHEDB() __builtin_amdgcn_sched_barrier(0)
#define BAR()    __builtin_amdgcn_s_barrier()

#define READ_A(BUF, MH)                                                      \
    _Pragma("unroll")                                                        \
    for (int mi = 0; mi < 4; ++mi) {                                         \
        const int row = (MH) * 128 + wm * 64 + mi * 16 + r15;                \
        af[mi][0] = lds_frag(BUF, row, 0, hi);                               \
        af[mi][1] = lds_frag(BUF, row, 1, hi);                               \
    }

#define READ_B(BUF, NH, DST)                                                 \
    _Pragma("unroll")                                                        \
    for (int ni = 0; ni < 2; ++ni) {                                         \
        const int row = (NH) * 128 + wn * 32 + ni * 16 + r15;                \
        DST[ni][0] = lds_frag(BUF, row, 0, hi);                              \
        DST[ni][1] = lds_frag(BUF, row, 1, hi);                              \
    }

#define MFMA16(MH, NH, BSET)                                                 \
    __builtin_amdgcn_s_setprio(1);                                           \
    _Pragma("unroll")                                                        \
    for (int mi = 0; mi < 4; ++mi)                                           \
        _Pragma("unroll")                                                    \
        for (int ni = 0; ni < 2; ++ni) {                                     \
            f32x4& ac = acc[(MH) * 4 + mi][(NH) * 2 + ni];                   \
            ac = __builtin_amdgcn_mfma_f32_16x16x32_f16(af[mi][0], BSET[ni][0], ac, 0, 0, 0); \
            ac = __builtin_amdgcn_mfma_f32_16x16x32_f16(af[mi][1], BSET[ni][1], ac, 0, 0, 0); \
        }                                                                    \
    __builtin_amdgcn_s_setprio(0);

// which: 0=A0 1=A1 2=B0 3=B1 ; stage order per tile: B0,A0,B1,A1
#define TILE(T, G0, G1, G2, G3)                                              \
  {                                                                          \
    const _Float16* Ab  = sA[(T) & 1];                                       \
    const _Float16* Bb  = sB[(T) & 1];                                       \
    const _Float16* Bb1 = sB[((T) + 1) & 1];                                 \
    /* P0: quadrant (0,0) */                                                 \
    READ_A(Ab, 0);                                                           \
    STAGE((T) + 2, 2);                                                       \
    BAR(); LGKM0(); SCHEDB();                                                \
    MFMA16(0, 0, bf0);                                                       \
    GATE(G0); BAR();                                                         \
    /* P1: quadrant (0,1) */                                                 \
    READ_B(Bb, 1, bf1);                                                      \
    STAGE((T) + 2, 0);                                                       \
    BAR(); LGKM0(); SCHEDB();                                                \
    MFMA16(0, 1, bf1);                                                       \
    GATE(G1); BAR();                                                         \
    /* P2: quadrant (1,0) */                                                 \
    READ_A(Ab, 1);                                                           \
    STAGE((T) + 2, 3);                                                       \
    BAR(); LGKM0(); SCHEDB();                                                \
    MFMA16(1, 0, bf0);                                                       \
    GATE(G2); BAR();                                                         \
    /* P3: quadrant (1,1); prefetch next tile's B0 into regs */              \
    READ_B(Bb1, 0, bf0);                                                     \
    STAGE((T) + 2, 1);                                                       \
    BAR(); LGKM0(); SCHEDB();                                                \
    MFMA16(1, 1, bf1);                                                       \
    GATE(G3); BAR();                                                         \
  }

__global__ __launch_bounds__(512, 2) void gemm4p_kernel(
    const _Float16* __restrict__ A,   // [M][K] qx
    const _Float16* __restrict__ B,   // [N][K] qw
    const float* __restrict__ bias,   // [N]
    float* __restrict__ C,            // [M][N]
    int M, int N, int K)
{
    constexpr int BK = 64;
    __shared__ _Float16 sA[2][256 * BK];   // 64 KiB
    __shared__ _Float16 sB[2][256 * BK];   // 64 KiB

    const int tid  = (int)threadIdx.x;
    const int lane = tid & 63;
    const int wave = tid >> 6;
    const int wm   = wave >> 2;    // 0..1
    const int wn   = wave & 3;     // 0..3
    const int r15  = lane & 15;
    const int hi   = lane >> 4;

    const int nbx = N >> 8;
    const int nwg = (M >> 8) * nbx;
    const int bid = (int)blockIdx.x;
    const int swz = (nwg & 7) ? bid : ((bid & 7) * (nwg >> 3) + (bid >> 3));
    const size_t bm0 = (size_t)(swz / nbx) << 8;
    const size_t bn0 = (size_t)(swz % nbx) << 8;

    const int nkt = K / BK;
    const _Float16* Agb = A + bm0 * K;
    const _Float16* Bgb = B + bn0 * K;

    auto STAGE = [&](int tile, int which) {
        if (tile >= nkt) return;
        const _Float16* g = (which < 2 ? Agb : Bgb) + (size_t)tile * BK;
        _Float16* lb = (which < 2 ? sA[tile & 1] : sB[tile & 1]);
        const int rb = (which & 1) << 7;
        #pragma unroll
        for (int rr = 0; rr < 2; ++rr) {
            const int row = rb + rr * 64 + (tid >> 3);
            const int sg  = (tid & 7) ^ (row & 7);
            gload_lds16(g + (size_t)row * K + sg * 8,
                        (char*)lb + ((rb + rr * 64) << 7) + (wave << 10));
        }
    };

    f32x4 acc[8][4] = {};
    f16x8 af[4][2], bf0[2][2], bf1[2][2];

    // prologue: stage tiles 0,1 in steady order (B0,A0,B1,A1 each) = 16 loads.
    // GATE(12): own-wave A0(0) landed (loads 3-4); barrier publishes all
    // waves' slices; then prefetch B[0][0] into regs (drained at t0.P0 gate).
    STAGE(0, 2); STAGE(0, 0); STAGE(0, 3); STAGE(0, 1);
    STAGE(1, 2); STAGE(1, 0); STAGE(1, 3); STAGE(1, 1);
    GATE("12");
    BAR();
    READ_B(sB[0], 0, bf0);

    for (int t = 0; t < nkt - 2; ++t)
        TILE(t, "12", "12", "12", "12");
    TILE(nkt - 2, "0", "0", "0", "0");
    TILE(nkt - 1, "0", "0", "0", "0");

    // epilogue: C/D layout col = lane&15, row = (lane>>4)*4 + reg
    #pragma unroll
    for (int nf = 0; nf < 4; ++nf) {
        const size_t col = bn0 + (size_t)((nf >> 1) * 128 + wn * 32 + (nf & 1) * 16 + r15);
        const float bv = bias[col];
        #pragma unroll
        for (int mf = 0; mf < 8; ++mf) {
            const size_t row0 = bm0 + (size_t)((mf >> 2) * 128 + wm * 64 + (mf & 3) * 16 + hi * 4);
            #pragma unroll
            for (int r = 0; r < 4; ++r)
                C[(row0 + r) * N + col] = acc[mf][nf][r] + bv;
        }
    }
}

// ---------------------------------------------------------------------------
extern "C" void kernel_launch(void* const* d_in, const int* in_sizes, int n_in,
                              void* d_out, int out_size, void* d_ws, size_t ws_size,
                              hipStream_t stream) {
    const float* x    = (const float*)d_in[0];
    const float* w    = (const float*)d_in[1];
    const float* bias = (const float*)d_in[2];
    const float* aw   = (const float*)d_in[3];
    const float* aA   = (const float*)d_in[4];

    const int    OUT = in_sizes[2];
    const size_t wsz = (size_t)in_sizes[1];
    const int    IN  = (int)(wsz / OUT);
    const int    M   = in_sizes[0] / IN;    // 8192
    const int    N   = OUT;                 // 4096
    const int    K   = IN;                  // 4096

    char* ws = (char*)d_ws;
    _Float16* qx = (_Float16*)ws;                                   // M*K*2
    _Float16* qw = (_Float16*)(ws + (size_t)M * K * 2);             // N*K*2
    float* afeat   = (float*)(ws + (size_t)M * K * 2 + (size_t)N * K * 2);
    float* partial = afeat + K;                                     // 32*K

    const int NCHUNK = 32;
    dim3 g1(K / 256, NCHUNK);
    colsum_partial_kernel<<<g1, 256, 0, stream>>>(aA, partial, K, OUT / NCHUNK);
    colsum_final_kernel<<<K / 256, 256, 0, stream>>>(partial, afeat, K, NCHUNK,
                                                     1.0f / (float)OUT);

    // quant_x: total threads = (IN/4) * 512 -> blocks = IN/2 / 256 = IN/512*... 
    const int qx_blocks = (IN / 4) * 512 / 256;   // 2048 for IN=4096
    quant_x_kernel<<<qx_blocks, 256, 0, stream>>>(x, afeat, (f16x4*)qx, IN, M);
    quant_w_kernel<<<2048, 256, 0, stream>>>(w, aw, (f16x4*)qw,
                                             (size_t)N * K / 4);

    const int nwg = (M / 256) * (N / 256);
    gemm4p_kernel<<<nwg, 512, 0, stream>>>(qx, qw, bias, (float*)d_out,
                                           M, N, K);
}

// Round 6
// 389.895 us; speedup vs baseline: 1.2242x; 1.2242x over previous
//
#include <hip/hip_runtime.h>
#include <hip/hip_fp16.h>
#include <cstdint>
#include <cstddef>

typedef _Float16 f16x8 __attribute__((ext_vector_type(8)));
typedef _Float16 f16x4 __attribute__((ext_vector_type(4)));
typedef float    f32x4 __attribute__((ext_vector_type(4)));

// ---------------------------------------------------------------------------
// fake-quant with fractional bit-width interpolation (matches jax reference)
// ---------------------------------------------------------------------------
__device__ __forceinline__ float quant_interp(float v, float alpha) {
    float a    = fmaxf(alpha, 1.0f);
    float blo  = floorf(a);
    float frac = a - blo;
    float slo  = exp2f(blo) - 1.0f;
    float shi  = 2.0f * slo + 1.0f;
    float rslo = __builtin_amdgcn_rcpf(slo);
    float rshi = __builtin_amdgcn_rcpf(shi);
    float c    = fminf(fmaxf(v, -1.0f), 1.0f);
    float qlo  = rintf(c * slo) * rslo;
    float qhi  = rintf(c * shi) * rshi;
    return (1.0f - frac) * qlo + frac * qhi;
}

// ---------------------------------------------------------------------------
// column mean of alpha_a [OUT][IN] -> a_feat [IN], deterministic two-pass
// ---------------------------------------------------------------------------
__global__ void colsum_partial_kernel(const float* __restrict__ aA,
                                      float* __restrict__ partial,
                                      int IN, int rows_per) {
    int col = blockIdx.x * blockDim.x + threadIdx.x;
    size_t r0 = (size_t)blockIdx.y * rows_per;
    float s = 0.f;
    for (int r = 0; r < rows_per; ++r)
        s += aA[(r0 + r) * (size_t)IN + col];
    partial[(size_t)blockIdx.y * IN + col] = s;
}

__global__ void colsum_final_kernel(const float* __restrict__ partial,
                                    float* __restrict__ afeat,
                                    int IN, int nchunk, float inv) {
    int col = blockIdx.x * blockDim.x + threadIdx.x;
    float s = 0.f;
    for (int c = 0; c < nchunk; ++c)
        s += partial[(size_t)c * IN + col];
    afeat[col] = s * inv;
}

// ---------------------------------------------------------------------------
// quantize x [M][IN] with per-column alpha -> fp16 (R3 version: grid-stride)
// ---------------------------------------------------------------------------
__global__ void quant_x_kernel(const float* __restrict__ x,
                               const float* __restrict__ afeat,
                               f16x4* __restrict__ qx, int IN, size_t n4) {
    size_t i = (size_t)blockIdx.x * blockDim.x + threadIdx.x;
    size_t stride = (size_t)gridDim.x * blockDim.x;
    for (; i < n4; i += stride) {
        size_t e = i * 4;
        int col = (int)(e % (size_t)IN);
        f32x4 xv = *(const f32x4*)(x + e);
        f32x4 av = *(const f32x4*)(afeat + col);
        f16x4 o;
        #pragma unroll
        for (int j = 0; j < 4; ++j) o[j] = (_Float16)quant_interp(xv[j], av[j]);
        qx[i] = o;
    }
}

__global__ void quant_w_kernel(const float* __restrict__ w,
                               const float* __restrict__ aw,
                               f16x4* __restrict__ qw, size_t n4) {
    size_t i = (size_t)blockIdx.x * blockDim.x + threadIdx.x;
    size_t stride = (size_t)gridDim.x * blockDim.x;
    for (; i < n4; i += stride) {
        f32x4 wv = *(const f32x4*)(w + i * 4);
        f32x4 av = *(const f32x4*)(aw + i * 4);
        f16x4 o;
        #pragma unroll
        for (int j = 0; j < 4; ++j) o[j] = (_Float16)quant_interp(wv[j], av[j]);
        qw[i] = o;
    }
}

// ---------------------------------------------------------------------------
// 256x256 NT GEMM, fp16 in / fp32 out. R3's 2-phase structure MINUS the
// lockstep forcers: NO pre-MFMA barrier, NO manual lgkmcnt(0), NO
// sched_barrier. The compiler emits COUNTED lgkmcnt per MFMA's actual deps
// (m97 asm evidence), so group-k MFMAs overlap group-k+1 ds_reads — LDS pipe
// (~2800 cyc/tile/CU) hides under MFMA pipe (~2483 cyc) instead of adding.
//   Phase 0: read A-half0 (8xb128) + all B (8xb128, tile-resident);
//            stage B1,A1(t+1) -> buf^1; 32 MFMA; vmcnt(8); s_barrier.
//   Phase 1: read A-half1 (8xb128); stage A0,B0(t+2) -> buf; 32 MFMA;
//            vmcnt(6); s_barrier.
// WAR safety: every read is consumed by an MFMA before its wave reaches the
// phase-end barrier (counted waits => reads retired), and every STAGE target
// was last read >=1 barrier earlier. Gates sit BEFORE barriers so per-wave
// vmcnt + barrier publishes all waves' staged slices. Barriers are inline-asm
// with "memory" clobber so ds_reads cannot hoist above the sync point (own
// vmcnt doesn't cover other waves' stages). Last 3 tiles gate vmcnt(0)
// (stage-skip shrinks the queue; counted gates would under-wait).
// XOR slot swizzle: phys slot = logical ^ (row&7); inverse applied to the
// GLOBAL source, linear LDS dest (rule #21). 0 bank conflicts (measured).
// ---------------------------------------------------------------------------
__device__ __forceinline__ void gload_lds16(const void* g, void* l) {
    __builtin_amdgcn_global_load_lds(
        (const __attribute__((address_space(1))) void*)g,
        (__attribute__((address_space(3))) void*)l, 16, 0, 0);
}

__device__ __forceinline__ f16x8 lds_frag(const _Float16* buf, int row, int ks, int hi) {
    const int sl = (ks * 4 + hi) ^ (row & 7);
    return *(const f16x8*)((const char*)buf + row * 128 + sl * 16);
}

#define GATE(N)  asm volatile("s_waitcnt vmcnt(" N ")" ::: "memory")
#define BAR()    asm volatile("s_barrier" ::: "memory")

#define READ_A(BUF, MH)                                                      \
    _Pragma("unroll")                                                        \
    for (int mi = 0; mi < 4; ++mi) {                                         \
        const int row = (MH) * 128 + wm * 64 + mi * 16 + r15;                \
        af[mi][0] = lds_frag(BUF, row, 0, hi);                               \
        af[mi][1] = lds_frag(BUF, row, 1, hi);                               \
    }

#define READ_BF(BUF)                                                         \
    _Pragma("unroll")                                                        \
    for (int nf = 0; nf < 4; ++nf) {                                         \
        const int row = (nf >> 1) * 128 + wn * 32 + (nf & 1) * 16 + r15;     \
        bf[nf][0] = lds_frag(BUF, row, 0, hi);                               \
        bf[nf][1] = lds_frag(BUF, row, 1, hi);                               \
    }

#define MFMA32(MH)                                                           \
    __builtin_amdgcn_s_setprio(1);                                           \
    _Pragma("unroll")                                                        \
    for (int mi = 0; mi < 4; ++mi)                                           \
        _Pragma("unroll")                                                    \
        for (int nf = 0; nf < 4; ++nf) {                                     \
            f32x4& ac = acc[(MH) * 4 + mi][nf];                              \
            ac = __builtin_amdgcn_mfma_f32_16x16x32_f16(af[mi][0], bf[nf][0], ac, 0, 0, 0); \
            ac = __builtin_amdgcn_mfma_f32_16x16x32_f16(af[mi][1], bf[nf][1], ac, 0, 0, 0); \
        }                                                                    \
    __builtin_amdgcn_s_setprio(0);

// which: 0=A0 1=A1 2=B0 3=B1
#define TILE2(T, G0, G1)                                                     \
  {                                                                          \
    const _Float16* Ab = sA[(T) & 1];                                        \
    const _Float16* Bb = sB[(T) & 1];                                        \
    f16x8 af[4][2];                                                          \
    /* phase 0: A-half0 + all B; stage B1,A1(t+1) */                         \
    READ_A(Ab, 0);                                                           \
    READ_BF(Bb);                                                             \
    STAGE((T) + 1, 3); STAGE((T) + 1, 1);                                    \
    MFMA32(0);                                                               \
    GATE(G0); BAR();                                                         \
    /* phase 1: A-half1; stage A0,B0(t+2) */                                 \
    READ_A(Ab, 1);                                                           \
    STAGE((T) + 2, 0); STAGE((T) + 2, 2);                                    \
    MFMA32(1);                                                               \
    GATE(G1); BAR();                                                         \
  }

__global__ __launch_bounds__(512, 2) void gemm2pf_kernel(
    const _Float16* __restrict__ A,   // [M][K] qx
    const _Float16* __restrict__ B,   // [N][K] qw
    const float* __restrict__ bias,   // [N]
    float* __restrict__ C,            // [M][N]
    int M, int N, int K)
{
    constexpr int BK = 64;
    __shared__ _Float16 sA[2][256 * BK];   // 64 KiB
    __shared__ _Float16 sB[2][256 * BK];   // 64 KiB

    const int tid  = (int)threadIdx.x;
    const int lane = tid & 63;
    const int wave = tid >> 6;
    const int wm   = wave >> 2;    // 0..1
    const int wn   = wave & 3;     // 0..3
    const int r15  = lane & 15;
    const int hi   = lane >> 4;

    const int nbx = N >> 8;
    const int nwg = (M >> 8) * nbx;
    const int bid = (int)blockIdx.x;
    const int swz = (nwg & 7) ? bid : ((bid & 7) * (nwg >> 3) + (bid >> 3));
    const size_t bm0 = (size_t)(swz / nbx) << 8;
    const size_t bn0 = (size_t)(swz % nbx) << 8;

    const int nkt = K / BK;
    const _Float16* Agb = A + bm0 * K;
    const _Float16* Bgb = B + bn0 * K;

    auto STAGE = [&](int tile, int which) {
        if (tile >= nkt) return;
        const _Float16* g = (which < 2 ? Agb : Bgb) + (size_t)tile * BK;
        _Float16* lb = (which < 2 ? sA[tile & 1] : sB[tile & 1]);
        const int rb = (which & 1) << 7;
        #pragma unroll
        for (int rr = 0; rr < 2; ++rr) {
            const int row = rb + rr * 64 + (tid >> 3);
            const int sg  = (tid & 7) ^ (row & 7);
            gload_lds16(g + (size_t)row * K + sg * 8,
                        (char*)lb + ((rb + rr * 64) << 7) + (wave << 10));
        }
    };

    f32x4 acc[8][4] = {};
    f16x8 bf[4][2];

    // prologue: A0(0),B0(0),B1(0),A1(0),A0(1),B0(1) = 12 loads;
    // vmcnt(6) drains tile0's A0,B0,B1; leaves [A1(0),A0(1),B0(1)] in flight
    STAGE(0, 0); STAGE(0, 2); STAGE(0, 3); STAGE(0, 1);
    STAGE(1, 0); STAGE(1, 2);
    GATE("6"); BAR();

    // steady-state FIFO: ph0 gate(8) drains A1(t); ph1 gate(6) drains
    // A0,B0,B1 of t+1 (exactly what the next tile's phase-0 reads need)
    int t = 0;
    for (; t < nkt - 3; ++t)
        TILE2(t, "8", "6");
    for (; t < nkt; ++t)           // tail: stages skip -> full drain is safe
        TILE2(t, "0", "0");

    // epilogue: C/D layout col = lane&15, row = (lane>>4)*4 + reg
    #pragma unroll
    for (int nf = 0; nf < 4; ++nf) {
        const size_t col = bn0 + (size_t)((nf >> 1) * 128 + wn * 32 + (nf & 1) * 16 + r15);
        const float bv = bias[col];
        #pragma unroll
        for (int mf = 0; mf < 8; ++mf) {
            const size_t row0 = bm0 + (size_t)((mf >> 2) * 128 + wm * 64 + (mf & 3) * 16 + hi * 4);
            #pragma unroll
            for (int r = 0; r < 4; ++r)
                C[(row0 + r) * N + col] = acc[mf][nf][r] + bv;
        }
    }
}

// ---------------------------------------------------------------------------
extern "C" void kernel_launch(void* const* d_in, const int* in_sizes, int n_in,
                              void* d_out, int out_size, void* d_ws, size_t ws_size,
                              hipStream_t stream) {
    const float* x    = (const float*)d_in[0];
    const float* w    = (const float*)d_in[1];
    const float* bias = (const float*)d_in[2];
    const float* aw   = (const float*)d_in[3];
    const float* aA   = (const float*)d_in[4];

    const int    OUT = in_sizes[2];
    const size_t wsz = (size_t)in_sizes[1];
    const int    IN  = (int)(wsz / OUT);
    const int    M   = in_sizes[0] / IN;    // 8192
    const int    N   = OUT;                 // 4096
    const int    K   = IN;                  // 4096

    char* ws = (char*)d_ws;
    _Float16* qx = (_Float16*)ws;                                   // M*K*2
    _Float16* qw = (_Float16*)(ws + (size_t)M * K * 2);             // N*K*2
    float* afeat   = (float*)(ws + (size_t)M * K * 2 + (size_t)N * K * 2);
    float* partial = afeat + K;                                     // 32*K

    const int NCHUNK = 32;
    dim3 g1(K / 256, NCHUNK);
    colsum_partial_kernel<<<g1, 256, 0, stream>>>(aA, partial, K, OUT / NCHUNK);
    colsum_final_kernel<<<K / 256, 256, 0, stream>>>(partial, afeat, K, NCHUNK,
                                                     1.0f / (float)OUT);

    quant_x_kernel<<<2048, 256, 0, stream>>>(x, afeat, (f16x4*)qx, K,
                                             (size_t)M * K / 4);
    quant_w_kernel<<<2048, 256, 0, stream>>>(w, aw, (f16x4*)qw,
                                             (size_t)N * K / 4);

    const int nwg = (M / 256) * (N / 256);
    gemm2pf_kernel<<<nwg, 512, 0, stream>>>(qx, qw, bias, (float*)d_out,
                                            M, N, K);
}